// Round 1
// baseline (26.482 us; speedup 1.0000x reference)
//
#include <hip/hip_runtime.h>
#include <math.h>

// Problem constants (from reference):
//   R=150, A=6, S=3, P=32768, B=8, MIN_PPM=10, MAX_PPM=195, B2_FLOOR=0.001
#define NRES   150
#define NATOM  6
#define NS     3
#define NPK    (NRES * NATOM * NS)   // 2700
#define NBG    8
#define NE     (NPK + NBG)           // 2708
#define NEP    2720                  // padded to multiple of 8*2 for chunking / float4
#define P_PTS  32768

#define CHUNKS       8
#define EPC          (NEP / CHUNKS)  // 340 entries per chunk
#define PTS_PER_BLK  64
#define MAIN_THREADS 512             // 64 points x 8 chunks
#define MAIN_BLOCKS  (P_PTS / PTS_PER_BLK)  // 512

// ---------------------------------------------------------------------------
// Prep: build compact (mu, w) table. w folds in softmax(a) and the NaN mask.
// The (half/pi) Lorentzian prefactor cancels in spec/sum(spec) and is dropped.
// ---------------------------------------------------------------------------
__global__ void GD_prep(const float* __restrict__ shift,
                        const float* __restrict__ a,
                        const float* __restrict__ offset,
                        const float* __restrict__ side_off,
                        const float* __restrict__ re_ref,
                        const float* __restrict__ bg_means,
                        float2* __restrict__ entries) {
    __shared__ float soft[NRES][NS];
    const int t = threadIdx.x;
    for (int r = t; r < NRES; r += 256) {
        float a0 = a[r * NS + 0], a1 = a[r * NS + 1], a2 = a[r * NS + 2];
        float m = fmaxf(a0, fmaxf(a1, a2));
        float e0 = expf(a0 - m), e1 = expf(a1 - m), e2 = expf(a2 - m);
        float inv = 1.0f / (e0 + e1 + e2);
        soft[r][0] = e0 * inv; soft[r][1] = e1 * inv; soft[r][2] = e2 * inv;
    }
    __syncthreads();
    const float rr = re_ref[0];
    for (int i = t; i < NEP; i += 256) {
        float mu = 0.0f, w = 0.0f;
        if (i < NPK) {
            float sh = shift[i];
            bool valid = !(sh != sh);            // !isnan
            int r = i / (NATOM * NS);
            int s = i % NS;
            mu = (valid ? sh : 0.0f) + offset[i] - rr;
            w  = valid ? soft[r][s] : 0.0f;
        } else if (i < NE) {
            int bi = i - NPK;
            mu = bg_means[bi] + side_off[bi] - rr;
            w  = 1.0f;
        }
        entries[i] = make_float2(mu, w);
    }
}

// ---------------------------------------------------------------------------
// Main: each block computes 64 points; 8 entry-chunks in parallel (512 thr).
// spec[p] = sum_i w_i / ((x_p - mu_i)^2 + half^2)   (prefactor cancelled)
// Writes unnormalized spec to d_out, per-block sums to blockpart.
// ---------------------------------------------------------------------------
__global__ __launch_bounds__(MAIN_THREADS) void GD_spec(
        const float* __restrict__ ppm,
        const float* __restrict__ b,
        const float2* __restrict__ entries,
        float* __restrict__ out,
        float* __restrict__ blockpart) {
    __shared__ float2 ent[NEP];
    __shared__ float part[CHUNKS][PTS_PER_BLK];

    const int t = threadIdx.x;
    // stage entry table to LDS (float4 = 2 entries per load)
    {
        const float4* src = (const float4*)entries;
        float4* dst = (float4*)ent;
        for (int i = t; i < NEP / 2; i += MAIN_THREADS) dst[i] = src[i];
    }
    __syncthreads();

    const float bb = b[0];
    const float b2 = fmaxf(bb * bb, 0.001f);
    const float half = 0.5f * b2;
    const float h2 = half * half;

    const int plocal = t & (PTS_PER_BLK - 1);
    const int chunk = t >> 6;                       // 0..7
    const int p = blockIdx.x * PTS_PER_BLK + plocal;
    const float x = ppm[p];

    const float4* e4 = (const float4*)(ent + chunk * EPC);  // 2720B-aligned
    float acc0 = 0.0f, acc1 = 0.0f, acc2 = 0.0f, acc3 = 0.0f;
    for (int i = 0; i < EPC / 2; i += 2) {          // 85 iters x 4 entries
        float4 u = e4[i];
        float4 v = e4[i + 1];
        float d0 = x - u.x;
        float d1 = x - u.z;
        float d2 = x - v.x;
        float d3 = x - v.z;
        acc0 += u.y * __builtin_amdgcn_rcpf(__builtin_fmaf(d0, d0, h2));
        acc1 += u.w * __builtin_amdgcn_rcpf(__builtin_fmaf(d1, d1, h2));
        acc2 += v.y * __builtin_amdgcn_rcpf(__builtin_fmaf(d2, d2, h2));
        acc3 += v.w * __builtin_amdgcn_rcpf(__builtin_fmaf(d3, d3, h2));
    }
    part[chunk][plocal] = (acc0 + acc1) + (acc2 + acc3);
    __syncthreads();

    if (t < PTS_PER_BLK) {                          // exactly wave 0
        float s = 0.0f;
        #pragma unroll
        for (int c = 0; c < CHUNKS; ++c) s += part[c][t];
        out[p] = s;                                  // t == plocal here
        // deterministic wave-64 reduction for the block sum
        float v = s;
        for (int off = 32; off > 0; off >>= 1) v += __shfl_down(v, off, 64);
        if (t == 0) blockpart[blockIdx.x] = v;
    }
}

// ---------------------------------------------------------------------------
// Normalize: every block redundantly reduces the 512 block partials (fp64,
// deterministic), then scales its 256 output points in place.
// ---------------------------------------------------------------------------
__global__ void GD_norm(const float* __restrict__ blockpart,
                        float* __restrict__ out) {
    __shared__ double tot[256];
    const int t = threadIdx.x;
    tot[t] = (double)blockpart[t] + (double)blockpart[t + 256];
    __syncthreads();
    for (int s = 128; s > 0; s >>= 1) {
        if (t < s) tot[t] += tot[t + s];
        __syncthreads();
    }
    const float inv = (float)(1.0 / tot[0]);
    const int p = blockIdx.x * 256 + t;
    out[p] *= inv;
}

extern "C" void kernel_launch(void* const* d_in, const int* in_sizes, int n_in,
                              void* d_out, int out_size, void* d_ws, size_t ws_size,
                              hipStream_t stream) {
    const float* ppm      = (const float*)d_in[0];
    const float* shift    = (const float*)d_in[1];
    const float* a        = (const float*)d_in[2];
    const float* offset   = (const float*)d_in[3];
    const float* side_off = (const float*)d_in[4];
    const float* re_ref   = (const float*)d_in[5];
    const float* b        = (const float*)d_in[6];
    const float* bg_means = (const float*)d_in[7];
    float* out = (float*)d_out;

    // ws layout: [0,2048) block partials (512 floats); [2048, 2048+21760) entries
    float*  blockpart = (float*)d_ws;
    float2* entries   = (float2*)((char*)d_ws + 2048);

    GD_prep<<<1, 256, 0, stream>>>(shift, a, offset, side_off, re_ref, bg_means,
                                   entries);
    GD_spec<<<MAIN_BLOCKS, MAIN_THREADS, 0, stream>>>(ppm, b, entries, out,
                                                      blockpart);
    GD_norm<<<P_PTS / 256, 256, 0, stream>>>(blockpart, out);
}

// Round 2
// 24.741 us; speedup vs baseline: 1.0704x; 1.0704x over previous
//
#include <hip/hip_runtime.h>
#include <math.h>

// Problem constants (from reference):
//   R=150, A=6, S=3, P=32768, B=8, MIN_PPM=10, MAX_PPM=195, B2_FLOOR=0.001
#define NRES   150
#define NATOM  6
#define NS     3
#define NPK    (NRES * NATOM * NS)   // 2700
#define NBG    8
#define NE     (NPK + NBG)           // 2708
#define NEP    2720                  // padded: 16 chunks x 170 entries
#define P_PTS  32768

#define CHUNKS       16
#define EPC          (NEP / CHUNKS)  // 170 entries per chunk (85 float4)
#define PTS_PER_BLK  64
#define MAIN_THREADS 1024            // 64 points x 16 chunks
#define MAIN_BLOCKS  (P_PTS / PTS_PER_BLK)  // 512

// ---------------------------------------------------------------------------
// Prep: build compact (mu, w) table in global ws. w folds in softmax(a) and
// the NaN mask. The (half/pi) prefactor cancels in spec/sum(spec) -> dropped.
// ---------------------------------------------------------------------------
__global__ void GD_prep(const float* __restrict__ shift,
                        const float* __restrict__ a,
                        const float* __restrict__ offset,
                        const float* __restrict__ side_off,
                        const float* __restrict__ re_ref,
                        const float* __restrict__ bg_means,
                        float2* __restrict__ entries) {
    __shared__ float soft[NRES][NS];
    const int t = threadIdx.x;
    for (int r = t; r < NRES; r += 256) {
        float a0 = a[r * NS + 0], a1 = a[r * NS + 1], a2 = a[r * NS + 2];
        float m = fmaxf(a0, fmaxf(a1, a2));
        float e0 = expf(a0 - m), e1 = expf(a1 - m), e2 = expf(a2 - m);
        float inv = 1.0f / (e0 + e1 + e2);
        soft[r][0] = e0 * inv; soft[r][1] = e1 * inv; soft[r][2] = e2 * inv;
    }
    __syncthreads();
    const float rr = re_ref[0];
    for (int i = t; i < NEP; i += 256) {
        float mu = 0.0f, w = 0.0f;
        if (i < NPK) {
            float sh = shift[i];
            bool valid = !(sh != sh);            // !isnan
            int r = i / (NATOM * NS);
            int s = i % NS;
            mu = (valid ? sh : 0.0f) + offset[i] - rr;
            w  = valid ? soft[r][s] : 0.0f;
        } else if (i < NE) {
            int bi = i - NPK;
            mu = bg_means[bi] + side_off[bi] - rr;
            w  = 1.0f;
        }
        entries[i] = make_float2(mu, w);         // padding: mu=0,w=0 (harmless)
    }
}

// ---------------------------------------------------------------------------
// Main: block = 64 points x 16 entry-chunks (1024 thr, 16 waves).
// Entry stream is WAVE-UNIFORM -> scalar-cache loads (no LDS pipe, no
// staging barrier). spec[p] = sum_i w_i / ((x_p - mu_i)^2 + half^2).
// ---------------------------------------------------------------------------
__global__ __launch_bounds__(MAIN_THREADS) void GD_spec(
        const float* __restrict__ ppm,
        const float* __restrict__ b,
        const float2* __restrict__ entries,
        float* __restrict__ out,
        float* __restrict__ blockpart) {
    __shared__ float part[CHUNKS][PTS_PER_BLK];

    const int t = threadIdx.x;
    const int plocal = t & (PTS_PER_BLK - 1);
    // wave-uniform chunk index, forced into an SGPR
    const int chunk = __builtin_amdgcn_readfirstlane(t >> 6);   // 0..15
    const int p = blockIdx.x * PTS_PER_BLK + plocal;
    const float x = ppm[p];

    const float bb = b[0];
    const float b2 = fmaxf(bb * bb, 0.001f);
    const float half = 0.5f * b2;
    const float h2 = half * half;

    // uniform base pointer -> s_load_dwordx4 stream through the K$
    const float4* e4 = (const float4*)entries + chunk * (EPC / 2);
    float acc0 = 0.0f, acc1 = 0.0f;
    #pragma unroll 5
    for (int i = 0; i < EPC / 2; ++i) {          // 85 x (2 entries)
        float4 u = e4[i];                        // (mu0, w0, mu1, w1)
        float d0 = x - u.x;
        float d1 = x - u.z;
        acc0 += u.y * __builtin_amdgcn_rcpf(__builtin_fmaf(d0, d0, h2));
        acc1 += u.w * __builtin_amdgcn_rcpf(__builtin_fmaf(d1, d1, h2));
    }
    part[chunk][plocal] = acc0 + acc1;
    __syncthreads();

    if (t < PTS_PER_BLK) {                       // exactly wave 0
        float s = 0.0f;
        #pragma unroll
        for (int c = 0; c < CHUNKS; ++c) s += part[c][t];
        out[p] = s;                              // t == plocal here
        // deterministic wave-64 reduction for the block sum
        float v = s;
        for (int off = 32; off > 0; off >>= 1) v += __shfl_down(v, off, 64);
        if (t == 0) blockpart[blockIdx.x] = v;
    }
}

// ---------------------------------------------------------------------------
// Normalize: every block redundantly reduces the 512 block partials (fp64,
// deterministic), then scales its 256 output points in place.
// ---------------------------------------------------------------------------
__global__ void GD_norm(const float* __restrict__ blockpart,
                        float* __restrict__ out) {
    __shared__ double tot[256];
    const int t = threadIdx.x;
    tot[t] = (double)blockpart[t] + (double)blockpart[t + 256];
    __syncthreads();
    for (int s = 128; s > 0; s >>= 1) {
        if (t < s) tot[t] += tot[t + s];
        __syncthreads();
    }
    const float inv = (float)(1.0 / tot[0]);
    const int p = blockIdx.x * 256 + t;
    out[p] *= inv;
}

extern "C" void kernel_launch(void* const* d_in, const int* in_sizes, int n_in,
                              void* d_out, int out_size, void* d_ws, size_t ws_size,
                              hipStream_t stream) {
    const float* ppm      = (const float*)d_in[0];
    const float* shift    = (const float*)d_in[1];
    const float* a        = (const float*)d_in[2];
    const float* offset   = (const float*)d_in[3];
    const float* side_off = (const float*)d_in[4];
    const float* re_ref   = (const float*)d_in[5];
    const float* b        = (const float*)d_in[6];
    const float* bg_means = (const float*)d_in[7];
    float* out = (float*)d_out;

    // ws layout: [0,2048) block partials (512 floats); [2048, 2048+21760) entries
    float*  blockpart = (float*)d_ws;
    float2* entries   = (float2*)((char*)d_ws + 2048);

    GD_prep<<<1, 256, 0, stream>>>(shift, a, offset, side_off, re_ref, bg_means,
                                   entries);
    GD_spec<<<MAIN_BLOCKS, MAIN_THREADS, 0, stream>>>(ppm, b, entries, out,
                                                      blockpart);
    GD_norm<<<P_PTS / 256, 256, 0, stream>>>(blockpart, out);
}

// Round 3
// 21.381 us; speedup vs baseline: 1.2386x; 1.1571x over previous
//
#include <hip/hip_runtime.h>
#include <math.h>

// Problem constants: R=150, A=6, S=3, P=32768, B=8, B2_FLOOR=0.001
#define NRES   150
#define NATOM  6
#define NS     3
#define NPK    (NRES * NATOM * NS)   // 2700
#define NBG    8
#define NE     (NPK + NBG)           // 2708
#define NEP    2720                  // padded: 16 chunks x 170 entries
#define P_PTS  32768

#define CHUNKS       16
#define EPC          (NEP / CHUNKS)  // 170 entries per chunk (85 float4)
#define PTS_PER_BLK  64
#define MAIN_THREADS 1024            // 64 points x 16 chunks (16 waves)
#define MAIN_BLOCKS  (P_PTS / PTS_PER_BLK)  // 512

// ---------------------------------------------------------------------------
// Fused prep+spec: each block builds the full (mu, w) entry table in ITS OWN
// LDS (redundant across blocks, but fully parallel -- replaces the serial
// 1-block prep kernel + one graph gap). w folds softmax(a) and the NaN mask;
// the (half/pi) Lorentzian prefactor cancels in spec/sum(spec) -> dropped.
// Then: spec[p] = sum_i w_i / ((x_p - mu_i)^2 + half^2), 64 points/block,
// 16 entry-chunks in parallel.
// ---------------------------------------------------------------------------
__global__ __launch_bounds__(MAIN_THREADS) void GD_spec(
        const float* __restrict__ ppm,
        const float* __restrict__ shift,
        const float* __restrict__ a,
        const float* __restrict__ offset,
        const float* __restrict__ side_off,
        const float* __restrict__ re_ref,
        const float* __restrict__ b,
        const float* __restrict__ bg_means,
        float* __restrict__ out,
        float* __restrict__ blockpart) {
    __shared__ float4 entbuf[NEP / 2];           // (mu0,w0,mu1,w1) pairs, 21.25 KB
    __shared__ float  soft[NRES][NS];            // 1.8 KB
    __shared__ float  part[CHUNKS][PTS_PER_BLK]; // 4 KB

    const int t = threadIdx.x;

    // ---- phase 1: softmax rows (one thread per residue) ----
    if (t < NRES) {
        float a0 = a[t * NS + 0], a1 = a[t * NS + 1], a2 = a[t * NS + 2];
        float m = fmaxf(a0, fmaxf(a1, a2));
        float e0 = __expf(a0 - m), e1 = __expf(a1 - m), e2 = __expf(a2 - m);
        float inv = 1.0f / (e0 + e1 + e2);
        soft[t][0] = e0 * inv; soft[t][1] = e1 * inv; soft[t][2] = e2 * inv;
    }
    __syncthreads();

    // ---- phase 2: build entry table (<=3 entries per thread) ----
    {
        const float rr = re_ref[0];
        float2* ent2 = (float2*)entbuf;
        for (int i = t; i < NEP; i += MAIN_THREADS) {
            float mu = 0.0f, w = 0.0f;
            if (i < NPK) {
                float sh = shift[i];
                bool valid = !(sh != sh);        // !isnan
                int r = i / (NATOM * NS);
                int s = i % NS;
                mu = (valid ? sh : 0.0f) + offset[i] - rr;
                w  = valid ? soft[r][s] : 0.0f;
            } else if (i < NE) {
                int bi = i - NPK;
                mu = bg_means[bi] + side_off[bi] - rr;
                w  = 1.0f;
            }
            ent2[i] = make_float2(mu, w);        // padding: mu=0,w=0
        }
    }
    __syncthreads();

    // ---- phase 3: Lorentzian accumulation ----
    const float bb = b[0];
    const float b2 = fmaxf(bb * bb, 0.001f);
    const float half = 0.5f * b2;
    const float h2 = half * half;

    const int plocal = t & (PTS_PER_BLK - 1);
    const int chunk = t >> 6;                    // 0..15 (wave id)
    const int p = blockIdx.x * PTS_PER_BLK + plocal;
    const float x = ppm[p];

    const float4* e4 = entbuf + chunk * (EPC / 2);   // wave-uniform LDS stream
    float acc0 = 0.0f, acc1 = 0.0f;
    #pragma unroll 5
    for (int i = 0; i < EPC / 2; ++i) {          // 85 x (2 entries)
        float4 u = e4[i];                        // (mu0, w0, mu1, w1)
        float d0 = x - u.x;
        float d1 = x - u.z;
        float r0 = __builtin_amdgcn_rcpf(__builtin_fmaf(d0, d0, h2));
        float r1 = __builtin_amdgcn_rcpf(__builtin_fmaf(d1, d1, h2));
        acc0 = __builtin_fmaf(u.y, r0, acc0);
        acc1 = __builtin_fmaf(u.w, r1, acc1);
    }
    part[chunk][plocal] = acc0 + acc1;
    __syncthreads();

    // ---- phase 4: per-point reduce over chunks; block partial sum ----
    if (t < PTS_PER_BLK) {                       // exactly wave 0
        float s = 0.0f;
        #pragma unroll
        for (int c = 0; c < CHUNKS; ++c) s += part[c][t];
        out[p] = s;                              // t == plocal here
        float v = s;
        for (int off = 32; off > 0; off >>= 1) v += __shfl_down(v, off, 64);
        if (t == 0) blockpart[blockIdx.x] = v;
    }
}

// ---------------------------------------------------------------------------
// Normalize: 64 blocks x 512 threads, 1 point each. Wave 0 of each block
// reduces the 512 block partials (fp64, deterministic), broadcasts inv via
// LDS, then all threads scale their point in place.
// ---------------------------------------------------------------------------
__global__ __launch_bounds__(512) void GD_norm(
        const float* __restrict__ blockpart,
        float* __restrict__ out) {
    __shared__ float invs;
    const int t = threadIdx.x;
    if (t < 64) {
        double v = 0.0;
        #pragma unroll
        for (int k = 0; k < 8; ++k) v += (double)blockpart[t + 64 * k];
        for (int off = 32; off > 0; off >>= 1) v += __shfl_down(v, off, 64);
        if (t == 0) invs = (float)(1.0 / v);
    }
    __syncthreads();
    const int p = blockIdx.x * 512 + t;
    out[p] *= invs;
}

extern "C" void kernel_launch(void* const* d_in, const int* in_sizes, int n_in,
                              void* d_out, int out_size, void* d_ws, size_t ws_size,
                              hipStream_t stream) {
    const float* ppm      = (const float*)d_in[0];
    const float* shift    = (const float*)d_in[1];
    const float* a        = (const float*)d_in[2];
    const float* offset   = (const float*)d_in[3];
    const float* side_off = (const float*)d_in[4];
    const float* re_ref   = (const float*)d_in[5];
    const float* b        = (const float*)d_in[6];
    const float* bg_means = (const float*)d_in[7];
    float* out = (float*)d_out;

    float* blockpart = (float*)d_ws;             // 512 floats

    GD_spec<<<MAIN_BLOCKS, MAIN_THREADS, 0, stream>>>(
        ppm, shift, a, offset, side_off, re_ref, b, bg_means, out, blockpart);
    GD_norm<<<P_PTS / 512, 512, 0, stream>>>(blockpart, out);
}

// Round 4
// 20.921 us; speedup vs baseline: 1.2658x; 1.0220x over previous
//
#include <hip/hip_runtime.h>
#include <math.h>

// Problem constants: R=150, A=6, S=3, P=32768, B=8, B2_FLOOR=0.001
#define NRES   150
#define NATOM  6
#define NS     3
#define NPK    (NRES * NATOM * NS)   // 2700
#define NBG    8
#define NE     (NPK + NBG)           // 2708
#define NWAVES 16
#define RAW_PER_WAVE 170             // 16*170 = 2720 >= NE
#define MAXE   2720
#define P_PTS  32768
#define PTS_PER_BLK  64
#define MAIN_THREADS 1024            // 64 points x 16 waves
#define MAIN_BLOCKS  (P_PTS / PTS_PER_BLK)  // 512

// ---------------------------------------------------------------------------
// Fused prep+spec. Each block builds a COMPACTED (NaN-free) table of
// (mu, w) entries in LDS, stored pair-major as float4 (mu0, mu1, w0, w1),
// then accumulates  spec[p] = sum_i w_i / ((x_p-mu_i)^2 + half^2)
// using ONE v_rcp per entry PAIR:
//   w0/q0 + w1/q1 = (w0*q1 + w1*q0) * rcp(q0*q1)
// (The 1/pi*half prefactor cancels in spec/sum(spec) and is dropped.)
// Compaction is deterministic (wave-slice order + lane order).
// ---------------------------------------------------------------------------
__global__ __launch_bounds__(MAIN_THREADS) void GD_spec(
        const float* __restrict__ ppm,
        const float* __restrict__ shift,
        const float* __restrict__ a,
        const float* __restrict__ offset,
        const float* __restrict__ side_off,
        const float* __restrict__ re_ref,
        const float* __restrict__ b,
        const float* __restrict__ bg_means,
        float* __restrict__ out,
        float* __restrict__ blockpart) {
    __shared__ float quad[MAXE * 2];              // pair-major table, 21.76 KB
    __shared__ float soft[NRES][NS];              // 1.8 KB
    __shared__ float part[NWAVES][PTS_PER_BLK];   // 4 KB
    __shared__ int   counts[NWAVES];
    __shared__ int   bases[NWAVES + 1];

    const int t    = threadIdx.x;
    const int lane = t & 63;
    const int wid  = t >> 6;

    // ---- phase 1: softmax rows (one thread per residue) ----
    if (t < NRES) {
        float a0 = a[t * NS + 0], a1 = a[t * NS + 1], a2 = a[t * NS + 2];
        float m = fmaxf(a0, fmaxf(a1, a2));
        float e0 = __expf(a0 - m), e1 = __expf(a1 - m), e2 = __expf(a2 - m);
        float inv = 1.0f / (e0 + e1 + e2);
        soft[t][0] = e0 * inv; soft[t][1] = e1 * inv; soft[t][2] = e2 * inv;
    }
    __syncthreads();

    // ---- phase 2a: gather raw entries, ballot validity ----
    const float rr = re_ref[0];
    float mu_k[3], w_k[3];
    bool  val_k[3];
    unsigned long long masks[3];
    #pragma unroll
    for (int k = 0; k < 3; ++k) {
        int local = k * 64 + lane;
        int idx = wid * RAW_PER_WAVE + local;
        bool inslice = local < RAW_PER_WAVE;
        float mu = 0.0f, w = 0.0f; bool valid = false;
        if (inslice && idx < NPK) {
            float sh = shift[idx];
            if (!(sh != sh)) {                    // !isnan
                valid = true;
                int r = idx / (NATOM * NS);
                int s = idx % NS;
                mu = sh + offset[idx] - rr;
                w  = soft[r][s];
            }
        } else if (inslice && idx < NE) {
            int bi = idx - NPK;
            mu = bg_means[bi] + side_off[bi] - rr;
            w  = 1.0f; valid = true;
        }
        val_k[k] = valid; mu_k[k] = mu; w_k[k] = w;
        masks[k] = __ballot(valid);
    }
    if (lane == 0)
        counts[wid] = __popcll(masks[0]) + __popcll(masks[1]) + __popcll(masks[2]);
    __syncthreads();

    // ---- phase 2b: tiny serial scan for wave bases ----
    if (t == 0) {
        int acc = 0;
        for (int i = 0; i < NWAVES; ++i) { bases[i] = acc; acc += counts[i]; }
        bases[NWAVES] = acc;
    }
    __syncthreads();
    const int total  = bases[NWAVES];
    const int padded = (total + 31) & ~31;        // multiple of 32 entries

    // ---- phase 2c: compacted write, pair-major (mu0,mu1,w0,w1) ----
    {
        const int base = bases[wid];
        const unsigned long long lt = (1ull << lane) - 1ull;
        int run = 0;
        #pragma unroll
        for (int k = 0; k < 3; ++k) {
            if (val_k[k]) {
                int pos = base + run + (int)__popcll(masks[k] & lt);
                quad[(pos >> 1) * 4 + (pos & 1)]     = mu_k[k];
                quad[(pos >> 1) * 4 + 2 + (pos & 1)] = w_k[k];
            }
            run += (int)__popcll(masks[k]);
        }
    }
    if (t < padded - total) {                     // <=31 pad entries, w=0
        int pos = total + t;
        quad[(pos >> 1) * 4 + (pos & 1)]     = 0.0f;
        quad[(pos >> 1) * 4 + 2 + (pos & 1)] = 0.0f;
    }
    __syncthreads();

    // ---- phase 3: paired Lorentzian accumulation ----
    const float bb = b[0];
    const float b2 = fmaxf(bb * bb, 0.001f);
    const float hf = 0.5f * b2;
    const float h2 = hf * hf;

    const int p = blockIdx.x * PTS_PER_BLK + lane;
    const float x = ppm[p];

    const int S_c    = padded >> 4;               // entries per chunk (even)
    const int npairs = S_c >> 1;                  // pairs per chunk (even)
    const float4* e4 = (const float4*)quad + wid * npairs;

    float acc0 = 0.0f, acc1 = 0.0f;
    #pragma unroll 4
    for (int j = 0; j < npairs; j += 2) {
        float4 u = e4[j];                         // (mu0, mu1, w0, w1)
        float4 v = e4[j + 1];
        float d0 = x - u.x, d1 = x - u.y;
        float e0 = x - v.x, e1 = x - v.y;
        float q0 = __builtin_fmaf(d0, d0, h2);
        float q1 = __builtin_fmaf(d1, d1, h2);
        float s0 = __builtin_fmaf(e0, e0, h2);
        float s1 = __builtin_fmaf(e1, e1, h2);
        float num0 = __builtin_fmaf(u.z, q1, u.w * q0);
        float num1 = __builtin_fmaf(v.z, s1, v.w * s0);
        float r0 = __builtin_amdgcn_rcpf(q0 * q1);
        float r1 = __builtin_amdgcn_rcpf(s0 * s1);
        acc0 = __builtin_fmaf(num0, r0, acc0);
        acc1 = __builtin_fmaf(num1, r1, acc1);
    }
    part[wid][lane] = acc0 + acc1;
    __syncthreads();

    // ---- phase 4: per-point reduce over chunks; block partial sum ----
    if (t < PTS_PER_BLK) {                        // exactly wave 0
        float s = 0.0f;
        #pragma unroll
        for (int c = 0; c < NWAVES; ++c) s += part[c][t];
        out[p] = s;                               // t == lane here
        float v = s;
        for (int off = 32; off > 0; off >>= 1) v += __shfl_down(v, off, 64);
        if (t == 0) blockpart[blockIdx.x] = v;
    }
}

// ---------------------------------------------------------------------------
// Normalize: 64 blocks x 512 threads. Wave 0 reduces the 512 block partials
// (fp64, deterministic), broadcasts inv via LDS, all threads scale in place.
// ---------------------------------------------------------------------------
__global__ __launch_bounds__(512) void GD_norm(
        const float* __restrict__ blockpart,
        float* __restrict__ out) {
    __shared__ float invs;
    const int t = threadIdx.x;
    if (t < 64) {
        double v = 0.0;
        #pragma unroll
        for (int k = 0; k < 8; ++k) v += (double)blockpart[t + 64 * k];
        for (int off = 32; off > 0; off >>= 1) v += __shfl_down(v, off, 64);
        if (t == 0) invs = (float)(1.0 / v);
    }
    __syncthreads();
    const int p = blockIdx.x * 512 + t;
    out[p] *= invs;
}

extern "C" void kernel_launch(void* const* d_in, const int* in_sizes, int n_in,
                              void* d_out, int out_size, void* d_ws, size_t ws_size,
                              hipStream_t stream) {
    const float* ppm      = (const float*)d_in[0];
    const float* shift    = (const float*)d_in[1];
    const float* a        = (const float*)d_in[2];
    const float* offset   = (const float*)d_in[3];
    const float* side_off = (const float*)d_in[4];
    const float* re_ref   = (const float*)d_in[5];
    const float* b        = (const float*)d_in[6];
    const float* bg_means = (const float*)d_in[7];
    float* out = (float*)d_out;

    float* blockpart = (float*)d_ws;              // 512 floats

    GD_spec<<<MAIN_BLOCKS, MAIN_THREADS, 0, stream>>>(
        ppm, shift, a, offset, side_off, re_ref, b, bg_means, out, blockpart);
    GD_norm<<<P_PTS / 512, 512, 0, stream>>>(blockpart, out);
}